// Round 1
// baseline (345.134 us; speedup 1.0000x reference)
//
#include <hip/hip_runtime.h>
#include <cmath>

// Problem constants (from reference)
static constexpr int BERT   = 768;
static constexpr int HID    = 256;
static constexpr int NLAB   = 9;
static constexpr int NUFD   = 20;
static constexpr int NB     = 64;
static constexpr int NR     = 16;
static constexpr int NS     = 64;
static constexpr int PBD    = HID + NUFD;  // 276

// Workspace layout (float offsets). Total ~806,976 floats = 3.23 MB.
static constexpr size_t WS_A      = 0;          // [1024][768] masked row-sums
static constexpr size_t WS_COLSUM = 786432;     // [768]
static constexpr size_t WS_SUMB   = 787200;     // [1]
static constexpr size_t WS_CNT    = 787264;     // [1024]
static constexpr size_t WS_TSUM   = 788288;     // [1024]
static constexpr size_t WS_PB     = 789312;     // [64][276] p_batch

__device__ __forceinline__ float selu_f(float x) {
    const float alpha = 1.6732632423543772848170429916717f;
    const float scale = 1.0507009873554804934193349852946f;
    return scale * (x > 0.0f ? x : alpha * (expf(x) - 1.0f));
}

// K0: colsum[d] = sum_h W_proj[d][h]; sumb = sum(b_proj)
__global__ __launch_bounds__(256) void k0_colsum(
    const float* __restrict__ W, const float* __restrict__ bp,
    float* __restrict__ colsum, float* __restrict__ sumb) {
    int blk = blockIdx.x;
    int tid = threadIdx.x;
    if (blk < 3) {
        int d = blk * 256 + tid;
        const float4* W4 = (const float4*)W;
        float4 s4 = make_float4(0.f, 0.f, 0.f, 0.f);
        for (int h4 = 0; h4 < HID / 4; ++h4) {
            float4 v = W4[(size_t)d * (HID / 4) + h4];
            s4.x += v.x; s4.y += v.y; s4.z += v.z; s4.w += v.w;
        }
        colsum[d] = (s4.x + s4.y) + (s4.z + s4.w);
    } else {
        __shared__ float red[256];
        red[tid] = bp[tid];
        __syncthreads();
        for (int s = 128; s > 0; s >>= 1) {
            if (tid < s) red[tid] += red[tid + s];
            __syncthreads();
        }
        if (tid == 0) *sumb = red[0];
    }
}

// K1: one block per (b,r). Streams 64 rows x 768 f32, computes per-row
// t = row·colsum + sumb, mask = (t != 0), accumulates A = sum_s mask*row,
// cnt = sum_s mask, tsum = sum_s t. Memory-bound: 192 KB/block, 201 MB total.
__global__ __launch_bounds__(256) void k1_reduce(
    const float* __restrict__ inp, const float* __restrict__ colsum,
    const float* __restrict__ sumb, float* __restrict__ A,
    float* __restrict__ cnt_g, float* __restrict__ tsum_g) {
    int br  = blockIdx.x;
    int tid = threadIdx.x;
    int w = tid >> 6, l = tid & 63;

    const float4* cs4 = (const float4*)colsum;
    float4 c0 = cs4[l], c1 = cs4[64 + l], c2 = cs4[128 + l];
    float sb = *sumb;

    const float4* base = (const float4*)(inp + (size_t)br * NS * BERT);
    float4 a0 = make_float4(0.f,0.f,0.f,0.f);
    float4 a1 = make_float4(0.f,0.f,0.f,0.f);
    float4 a2 = make_float4(0.f,0.f,0.f,0.f);
    float cnt = 0.f, ts = 0.f;

    #pragma unroll 4
    for (int i = 0; i < 16; ++i) {
        int s = w * 16 + i;
        const float4* rp = base + (size_t)s * (BERT / 4);
        float4 v0 = rp[l];
        float4 v1 = rp[64 + l];
        float4 v2 = rp[128 + l];
        float p = v0.x*c0.x + v0.y*c0.y + v0.z*c0.z + v0.w*c0.w
                + v1.x*c1.x + v1.y*c1.y + v1.z*c1.z + v1.w*c1.w
                + v2.x*c2.x + v2.y*c2.y + v2.z*c2.z + v2.w*c2.w;
        #pragma unroll
        for (int off = 32; off > 0; off >>= 1) p += __shfl_xor(p, off);
        float t = p + sb;
        ts += t;
        if (t != 0.0f) {
            a0.x += v0.x; a0.y += v0.y; a0.z += v0.z; a0.w += v0.w;
            a1.x += v1.x; a1.y += v1.y; a1.z += v1.z; a1.w += v1.w;
            a2.x += v2.x; a2.y += v2.y; a2.z += v2.z; a2.w += v2.w;
            cnt += 1.0f;
        }
    }

    __shared__ float part[4][BERT];
    __shared__ float cw[4], tw[4];
    float* pw = part[w];
    ((float4*)pw)[l]       = a0;
    ((float4*)pw)[64 + l]  = a1;
    ((float4*)pw)[128 + l] = a2;
    if (l == 0) { cw[w] = cnt; tw[w] = ts; }
    __syncthreads();

    float* Ao = A + (size_t)br * BERT;
    for (int c = tid; c < BERT; c += 256)
        Ao[c] = (part[0][c] + part[1][c]) + (part[2][c] + part[3][c]);
    if (tid == 0) {
        cnt_g[br]  = (cw[0] + cw[1]) + (cw[2] + cw[3]);
        tsum_g[br] = (tw[0] + tw[1]) + (tw[2] + tw[3]);
    }
}

// K2: one block per batch row b.
//  M[b,:] = sum_r (rm_r / max(cnt_r,1e-9)) * A[b,r,:]
//  p_hn[b,h] = (M·W[:,h] + b_proj[h]*q) / max(sum_r rm, 1e-9)
//  uf = normalize(user_feats[b]) * user_w ; pb = [p_hn, uf]
//  r_stars[b] = selu(pb · W_rff + b_rff)
__global__ __launch_bounds__(256) void k2_perb(
    const float* __restrict__ A, const float* __restrict__ cnt_g,
    const float* __restrict__ tsum_g, const float* __restrict__ W_proj,
    const float* __restrict__ b_proj, const float* __restrict__ user_feats,
    const float* __restrict__ user_w, const float* __restrict__ W_rff,
    const float* __restrict__ b_rff, float* __restrict__ pb_out,
    float* __restrict__ r_out) {
    int b   = blockIdx.x;
    int tid = threadIdx.x;

    __shared__ float M[BERT];
    __shared__ float g[NR];
    __shared__ float scal[4];   // [0]=rden, [1]=q, [2]=inv_nrm
    __shared__ float pb[PBD];
    __shared__ float red[256];

    if (tid < NR) {
        float c  = cnt_g[b * NR + tid];
        float t  = tsum_g[b * NR + tid];
        float rm = (t != 0.0f) ? 1.0f : 0.0f;
        float den = fmaxf(c, 1e-9f);
        g[tid]       = rm / den;
        red[tid]     = rm;
        red[16 + tid] = rm * (c / den);
    }
    __syncthreads();
    if (tid == 0) {
        float srm = 0.f, sq = 0.f;
        for (int r = 0; r < NR; ++r) { srm += red[r]; sq += red[16 + r]; }
        scal[0] = fmaxf(srm, 1e-9f);
        scal[1] = sq;
    }
    // fold over r (uses g; coalesced A reads)
    for (int c = tid; c < BERT; c += 256) {
        float m = 0.f;
        #pragma unroll
        for (int r = 0; r < NR; ++r)
            m += g[r] * A[(size_t)(b * NR + r) * BERT + c];
        M[c] = m;
    }
    __syncthreads();   // M + scal visible

    // 768-dot for column tid (W reads coalesced across threads)
    float acc = 0.f;
    {
        const float* Wc = W_proj + tid;
        #pragma unroll 8
        for (int d = 0; d < BERT; ++d) acc += M[d] * Wc[(size_t)d * HID];
    }
    pb[tid] = (acc + b_proj[tid] * scal[1]) / scal[0];

    // user feature normalize
    if (tid < NUFD) red[tid] = user_feats[b * NUFD + tid];
    __syncthreads();
    if (tid == 0) {
        float s = 0.f;
        for (int j = 0; j < NUFD; ++j) s += red[j] * red[j];
        scal[2] = 1.0f / fmaxf(sqrtf(s), 1e-12f);
    }
    __syncthreads();
    if (tid < NUFD) pb[HID + tid] = red[tid] * scal[2] * user_w[tid];
    __syncthreads();   // pb fully written

    // emit p_batch
    pb_out[b * PBD + tid] = pb[tid];
    if (tid < PBD - HID) pb_out[b * PBD + HID + tid] = pb[HID + tid];

    // r_stars[b]
    float part = pb[tid] * W_rff[tid];
    if (tid < PBD - HID) part += pb[HID + tid] * W_rff[HID + tid];
    red[tid] = part;
    __syncthreads();
    for (int s = 128; s > 0; s >>= 1) {
        if (tid < s) red[tid] += red[tid + s];
        __syncthreads();
    }
    if (tid == 0) r_out[b] = selu_f(red[0] + b_rff[0]);
}

// K3: h_n = mean_b p_batch ; p_stars = selu(h_n @ W_pff + b_pff)
__global__ __launch_bounds__(320) void k3_final(
    const float* __restrict__ pb, const float* __restrict__ W_pff,
    const float* __restrict__ b_pff, float* __restrict__ out) {
    __shared__ float hn[PBD];
    int tid = threadIdx.x;
    if (tid < PBD) {
        float s = 0.f;
        for (int b = 0; b < NB; ++b) s += pb[b * PBD + tid];
        hn[tid] = s * (1.0f / NB);
    }
    __syncthreads();
    if (tid < NLAB) {
        float acc = 0.f;
        for (int j = 0; j < PBD; ++j) acc += hn[j] * W_pff[j * NLAB + tid];
        out[tid] = selu_f(acc + b_pff[tid]);
    }
}

extern "C" void kernel_launch(void* const* d_in, const int* in_sizes, int n_in,
                              void* d_out, int out_size, void* d_ws, size_t ws_size,
                              hipStream_t stream) {
    const float* inputs     = (const float*)d_in[0];
    const float* user_feats = (const float*)d_in[1];
    const float* W_proj     = (const float*)d_in[2];
    const float* b_proj     = (const float*)d_in[3];
    const float* W_rff      = (const float*)d_in[4];
    const float* b_rff      = (const float*)d_in[5];
    const float* W_pff      = (const float*)d_in[6];
    const float* b_pff      = (const float*)d_in[7];
    const float* user_w     = (const float*)d_in[8];
    float* out = (float*)d_out;     // [0..8]=p_stars, [9..72]=r_stars
    float* ws  = (float*)d_ws;

    float* A      = ws + WS_A;
    float* colsum = ws + WS_COLSUM;
    float* sumb   = ws + WS_SUMB;
    float* cntg   = ws + WS_CNT;
    float* tsumg  = ws + WS_TSUM;
    float* pb     = ws + WS_PB;

    hipLaunchKernelGGL(k0_colsum, dim3(4), dim3(256), 0, stream,
                       W_proj, b_proj, colsum, sumb);
    hipLaunchKernelGGL(k1_reduce, dim3(NB * NR), dim3(256), 0, stream,
                       inputs, colsum, sumb, A, cntg, tsumg);
    hipLaunchKernelGGL(k2_perb, dim3(NB), dim3(256), 0, stream,
                       A, cntg, tsumg, W_proj, b_proj, user_feats, user_w,
                       W_rff, b_rff, pb, out + NLAB);
    hipLaunchKernelGGL(k3_final, dim3(1), dim3(320), 0, stream,
                       pb, W_pff, b_pff, out);
}

// Round 2
// 303.454 us; speedup vs baseline: 1.1374x; 1.1374x over previous
//
#include <hip/hip_runtime.h>
#include <cmath>

// Problem constants (from reference)
static constexpr int BERT   = 768;
static constexpr int HID    = 256;
static constexpr int NLAB   = 9;
static constexpr int NUFD   = 20;
static constexpr int NB     = 64;
static constexpr int NR     = 16;
static constexpr int NS     = 64;
static constexpr int PBD    = HID + NUFD;  // 276

typedef float v4f __attribute__((ext_vector_type(4)));

// Workspace layout (float offsets). Total ~806,976 floats = 3.23 MB.
static constexpr size_t WS_A      = 0;          // [1024][768] masked row-sums
static constexpr size_t WS_COLSUM = 786432;     // [768]
static constexpr size_t WS_SUMB   = 787200;     // [1]
static constexpr size_t WS_CNT    = 787264;     // [1024]
static constexpr size_t WS_TSUM   = 788288;     // [1024]
static constexpr size_t WS_PB     = 789312;     // [64][276] p_batch

__device__ __forceinline__ float selu_f(float x) {
    const float alpha = 1.6732632423543772848170429916717f;
    const float scale = 1.0507009873554804934193349852946f;
    return scale * (x > 0.0f ? x : alpha * (expf(x) - 1.0f));
}

// K0: colsum[d] = sum_h W_proj[d][h]; sumb = sum(b_proj)
__global__ __launch_bounds__(256) void k0_colsum(
    const float* __restrict__ W, const float* __restrict__ bp,
    float* __restrict__ colsum, float* __restrict__ sumb) {
    int blk = blockIdx.x;
    int tid = threadIdx.x;
    if (blk < 3) {
        int d = blk * 256 + tid;
        const v4f* W4 = (const v4f*)W;
        v4f s4 = {0.f, 0.f, 0.f, 0.f};
        #pragma unroll 8
        for (int h4 = 0; h4 < HID / 4; ++h4)
            s4 += W4[(size_t)d * (HID / 4) + h4];
        colsum[d] = (s4.x + s4.y) + (s4.z + s4.w);
    } else {
        __shared__ float red[256];
        red[tid] = bp[tid];
        __syncthreads();
        for (int s = 128; s > 0; s >>= 1) {
            if (tid < s) red[tid] += red[tid + s];
            __syncthreads();
        }
        if (tid == 0) *sumb = red[0];
    }
}

// K1: one block per (b,r). Streams 64 rows x 768 f32 (nontemporal), per-row
// t = row.colsum + sumb, mask = (t != 0), accumulates A = sum_s mask*row,
// cnt = sum_s mask, tsum = sum_s t. Memory-bound: 192 KB/block, 201 MB total.
__global__ __launch_bounds__(256) void k1_reduce(
    const float* __restrict__ inp, const float* __restrict__ colsum,
    const float* __restrict__ sumb, float* __restrict__ A,
    float* __restrict__ cnt_g, float* __restrict__ tsum_g) {
    int br  = blockIdx.x;
    int tid = threadIdx.x;
    int w = tid >> 6, l = tid & 63;

    const v4f* cs4 = (const v4f*)colsum;
    v4f c0 = cs4[l], c1 = cs4[64 + l], c2 = cs4[128 + l];
    float sb = *sumb;

    const v4f* base = (const v4f*)(inp + (size_t)br * NS * BERT);
    v4f a0 = {0.f,0.f,0.f,0.f};
    v4f a1 = {0.f,0.f,0.f,0.f};
    v4f a2 = {0.f,0.f,0.f,0.f};
    float cnt = 0.f, ts = 0.f;

    #pragma unroll 4
    for (int i = 0; i < 16; ++i) {
        int s = w * 16 + i;
        const v4f* rp = base + (size_t)s * (BERT / 4);
        v4f v0 = __builtin_nontemporal_load(rp + l);
        v4f v1 = __builtin_nontemporal_load(rp + 64 + l);
        v4f v2 = __builtin_nontemporal_load(rp + 128 + l);
        float p = v0.x*c0.x + v0.y*c0.y + v0.z*c0.z + v0.w*c0.w
                + v1.x*c1.x + v1.y*c1.y + v1.z*c1.z + v1.w*c1.w
                + v2.x*c2.x + v2.y*c2.y + v2.z*c2.z + v2.w*c2.w;
        #pragma unroll
        for (int off = 32; off > 0; off >>= 1) p += __shfl_xor(p, off);
        float t = p + sb;
        ts += t;
        if (t != 0.0f) {            // wave-uniform branch
            a0 += v0; a1 += v1; a2 += v2;
            cnt += 1.0f;
        }
    }

    __shared__ float part[4][BERT];
    __shared__ float cw[4], tw[4];
    float* pw = part[w];
    ((v4f*)pw)[l]       = a0;
    ((v4f*)pw)[64 + l]  = a1;
    ((v4f*)pw)[128 + l] = a2;
    if (l == 0) { cw[w] = cnt; tw[w] = ts; }
    __syncthreads();

    float* Ao = A + (size_t)br * BERT;
    for (int c = tid; c < BERT; c += 256)
        Ao[c] = (part[0][c] + part[1][c]) + (part[2][c] + part[3][c]);
    if (tid == 0) {
        cnt_g[br]  = (cw[0] + cw[1]) + (cw[2] + cw[3]);
        tsum_g[br] = (tw[0] + tw[1]) + (tw[2] + tw[3]);
    }
}

// K2: grid 256 = (b, q) with q = h-quarter of 64 columns. Each block:
//   M[b,:] = sum_r (rm_r / max(cnt_r,1e-9)) * A[b,r,:]   (redundant x4, cheap)
//   p_hn[b,h] = (M.W[:,h] + b_proj[h]*qsum) / rden   for h in [q*64, q*64+64)
//   4-way k-split over d (serial depth 192) for load-latency hiding.
//   Block q==0 additionally emits uf = normalize(user_feats[b]) * user_w.
__global__ __launch_bounds__(256) void k2_gemm(
    const float* __restrict__ A, const float* __restrict__ cnt_g,
    const float* __restrict__ tsum_g, const float* __restrict__ W_proj,
    const float* __restrict__ b_proj, const float* __restrict__ user_feats,
    const float* __restrict__ user_w, float* __restrict__ pb_out) {
    int b   = blockIdx.x >> 2;
    int q   = blockIdx.x & 3;
    int tid = threadIdx.x;

    __shared__ float M[BERT];
    __shared__ float g[NR];
    __shared__ float scal[2];   // [0]=rden, [1]=qsum
    __shared__ float red[256];

    if (tid < NR) {
        float c  = cnt_g[b * NR + tid];
        float t  = tsum_g[b * NR + tid];
        float rm = (t != 0.0f) ? 1.0f : 0.0f;
        float den = fmaxf(c, 1e-9f);
        g[tid]        = rm / den;
        red[tid]      = rm;
        red[NR + tid] = rm * (c / den);
    }
    __syncthreads();
    if (tid == 0) {
        float srm = 0.f, sq = 0.f;
        for (int r = 0; r < NR; ++r) { srm += red[r]; sq += red[NR + r]; }
        scal[0] = fmaxf(srm, 1e-9f);
        scal[1] = sq;
    }
    for (int c = tid; c < BERT; c += 256) {
        float m = 0.f;
        #pragma unroll
        for (int r = 0; r < NR; ++r)
            m += g[r] * A[(size_t)(b * NR + r) * BERT + c];
        M[c] = m;
    }
    __syncthreads();   // M + scal visible

    // k-split dot: thread = (ks = tid>>6) x (hl = tid&63); d-slice of 192
    int hl = tid & 63;
    int ks = tid >> 6;
    int h  = q * 64 + hl;
    {
        const float* Wc = W_proj + h;
        float acc = 0.f;
        int d0 = ks * 192;
        #pragma unroll 16
        for (int j = 0; j < 192; ++j)
            acc += M[d0 + j] * Wc[(size_t)(d0 + j) * HID];
        red[tid] = acc;
    }
    __syncthreads();
    if (tid < 64) {
        float s = (red[tid] + red[64 + tid]) + (red[128 + tid] + red[192 + tid]);
        int hh = q * 64 + tid;
        pb_out[b * PBD + hh] = (s + b_proj[hh] * scal[1]) / scal[0];
    }

    if (q == 0) {
        __syncthreads();
        if (tid == 0) {
            float s = 0.f;
            for (int j = 0; j < NUFD; ++j) {
                float v = user_feats[b * NUFD + j];
                s += v * v;
            }
            red[0] = 1.0f / fmaxf(sqrtf(s), 1e-12f);
        }
        __syncthreads();
        if (tid < NUFD)
            pb_out[b * PBD + HID + tid] =
                user_feats[b * NUFD + tid] * red[0] * user_w[tid];
    }
}

// K3: r_stars[b] = selu(pb[b].W_rff + b_rff);
//     h_n = mean_b pb; p_stars = selu(h_n @ W_pff + b_pff)
__global__ __launch_bounds__(320) void k3_final(
    const float* __restrict__ pb, const float* __restrict__ W_rff,
    const float* __restrict__ b_rff, const float* __restrict__ W_pff,
    const float* __restrict__ b_pff, float* __restrict__ out) {
    __shared__ float hn[PBD];
    int tid = threadIdx.x;
    if (tid < PBD) {
        float s = 0.f;
        #pragma unroll 8
        for (int b = 0; b < NB; ++b) s += pb[b * PBD + tid];
        hn[tid] = s * (1.0f / NB);
    }
    __syncthreads();
    if (tid < NB) {
        int b = tid;
        float acc = 0.f;
        #pragma unroll 12
        for (int j = 0; j < PBD; ++j) acc += pb[b * PBD + j] * W_rff[j];
        out[NLAB + b] = selu_f(acc + b_rff[0]);
    } else if (tid >= 64 && tid < 64 + NLAB) {
        int lab = tid - 64;
        float acc = 0.f;
        #pragma unroll 12
        for (int j = 0; j < PBD; ++j) acc += hn[j] * W_pff[j * NLAB + lab];
        out[lab] = selu_f(acc + b_pff[lab]);
    }
}

extern "C" void kernel_launch(void* const* d_in, const int* in_sizes, int n_in,
                              void* d_out, int out_size, void* d_ws, size_t ws_size,
                              hipStream_t stream) {
    const float* inputs     = (const float*)d_in[0];
    const float* user_feats = (const float*)d_in[1];
    const float* W_proj     = (const float*)d_in[2];
    const float* b_proj     = (const float*)d_in[3];
    const float* W_rff      = (const float*)d_in[4];
    const float* b_rff      = (const float*)d_in[5];
    const float* W_pff      = (const float*)d_in[6];
    const float* b_pff      = (const float*)d_in[7];
    const float* user_w     = (const float*)d_in[8];
    float* out = (float*)d_out;     // [0..8]=p_stars, [9..72]=r_stars
    float* ws  = (float*)d_ws;

    float* A      = ws + WS_A;
    float* colsum = ws + WS_COLSUM;
    float* sumb   = ws + WS_SUMB;
    float* cntg   = ws + WS_CNT;
    float* tsumg  = ws + WS_TSUM;
    float* pb     = ws + WS_PB;

    hipLaunchKernelGGL(k0_colsum, dim3(4), dim3(256), 0, stream,
                       W_proj, b_proj, colsum, sumb);
    hipLaunchKernelGGL(k1_reduce, dim3(NB * NR), dim3(256), 0, stream,
                       inputs, colsum, sumb, A, cntg, tsumg);
    hipLaunchKernelGGL(k2_gemm, dim3(NB * 4), dim3(256), 0, stream,
                       A, cntg, tsumg, W_proj, b_proj, user_feats, user_w, pb);
    hipLaunchKernelGGL(k3_final, dim3(1), dim3(320), 0, stream,
                       pb, W_rff, b_rff, W_pff, b_pff, out);
}

// Round 3
// 299.237 us; speedup vs baseline: 1.1534x; 1.0141x over previous
//
#include <hip/hip_runtime.h>
#include <cmath>

// Problem constants (from reference)
static constexpr int BERT   = 768;
static constexpr int HID    = 256;
static constexpr int NLAB   = 9;
static constexpr int NUFD   = 20;
static constexpr int NB     = 64;
static constexpr int NR     = 16;
static constexpr int NS     = 64;
static constexpr int PBD    = HID + NUFD;  // 276

typedef float v4f __attribute__((ext_vector_type(4)));

// Workspace layout (float offsets). Total ~806,976 floats = 3.23 MB.
static constexpr size_t WS_A      = 0;          // [1024][768] masked row-sums
static constexpr size_t WS_COLSUM = 786432;     // [768]
static constexpr size_t WS_SUMB   = 787200;     // [1]
static constexpr size_t WS_CNT    = 787264;     // [1024]
static constexpr size_t WS_TSUM   = 788288;     // [1024]
static constexpr size_t WS_PB     = 789312;     // [64][276] p_batch

__device__ __forceinline__ float selu_f(float x) {
    const float alpha = 1.6732632423543772848170429916717f;
    const float scale = 1.0507009873554804934193349852946f;
    return scale * (x > 0.0f ? x : alpha * (expf(x) - 1.0f));
}

// K0: colsum[d] = sum_h W_proj[d][h]; sumb = sum(b_proj)
// 96 blocks x (8 rows x 32 lanes); block 96 reduces b_proj.
__global__ __launch_bounds__(256) void k0_colsum(
    const float* __restrict__ W, const float* __restrict__ bp,
    float* __restrict__ colsum, float* __restrict__ sumb) {
    int blk = blockIdx.x;
    int tid = threadIdx.x;
    if (blk < 96) {
        int row    = blk * 8 + (tid >> 5);
        int lane32 = tid & 31;
        const v4f* W4 = (const v4f*)(W + (size_t)row * HID);
        v4f s4 = W4[lane32 * 2] + W4[lane32 * 2 + 1];
        float s = (s4.x + s4.y) + (s4.z + s4.w);
        #pragma unroll
        for (int off = 16; off > 0; off >>= 1) s += __shfl_xor(s, off);
        if (lane32 == 0) colsum[row] = s;
    } else {
        __shared__ float red[256];
        red[tid] = bp[tid];
        __syncthreads();
        for (int s = 128; s > 0; s >>= 1) {
            if (tid < s) red[tid] += red[tid + s];
            __syncthreads();
        }
        if (tid == 0) *sumb = red[0];
    }
}

// K1: one block per (b,r). Streams 64 rows x 768 f32 (nontemporal).
// Rows are accumulated UNCONDITIONALLY while per-lane dot partials p[i]
// are kept in VGPRs; the 16 cross-lane reductions run once after the loop
// with full ILP (no shfl chain inside the streaming loop). Rows whose
// t == row.colsum + sumb == 0 (never, for random input) are subtracted
// in a rare correction pass. Memory-bound: 192 KB/block, 201 MB total.
__global__ __launch_bounds__(256) void k1_reduce(
    const float* __restrict__ inp, const float* __restrict__ colsum,
    const float* __restrict__ sumb, float* __restrict__ A,
    float* __restrict__ cnt_g, float* __restrict__ tsum_g) {
    int br  = blockIdx.x;
    int tid = threadIdx.x;
    int w = tid >> 6, l = tid & 63;

    const v4f* cs4 = (const v4f*)colsum;
    v4f c0 = cs4[l], c1 = cs4[64 + l], c2 = cs4[128 + l];
    float sb = *sumb;

    const v4f* base = (const v4f*)(inp + (size_t)br * NS * BERT);
    v4f a0 = {0.f,0.f,0.f,0.f};
    v4f a1 = {0.f,0.f,0.f,0.f};
    v4f a2 = {0.f,0.f,0.f,0.f};
    float p[16];

    #pragma unroll 4
    for (int i = 0; i < 16; ++i) {
        int s = w * 16 + i;
        const v4f* rp = base + (size_t)s * (BERT / 4);
        v4f v0 = __builtin_nontemporal_load(rp + l);
        v4f v1 = __builtin_nontemporal_load(rp + 64 + l);
        v4f v2 = __builtin_nontemporal_load(rp + 128 + l);
        p[i] = v0.x*c0.x + v0.y*c0.y + v0.z*c0.z + v0.w*c0.w
             + v1.x*c1.x + v1.y*c1.y + v1.z*c1.z + v1.w*c1.w
             + v2.x*c2.x + v2.y*c2.y + v2.z*c2.z + v2.w*c2.w;
        a0 += v0; a1 += v1; a2 += v2;
    }

    // Batched butterfly: 16 independent 6-step reductions, fully pipelined.
    #pragma unroll
    for (int off = 32; off > 0; off >>= 1) {
        #pragma unroll
        for (int i = 0; i < 16; ++i) p[i] += __shfl_xor(p[i], off);
    }

    float cnt = 0.f, ts = 0.f;
    bool anyzero = false;
    #pragma unroll
    for (int i = 0; i < 16; ++i) {
        float t = p[i] + sb;
        ts += t;
        cnt += (t != 0.0f) ? 1.0f : 0.0f;
        anyzero |= (t == 0.0f);
    }
    if (anyzero) {   // rare-path exactness: remove rows the mask excludes
        for (int i = 0; i < 16; ++i) {
            if (p[i] + sb == 0.0f) {
                int s = w * 16 + i;
                const v4f* rp = base + (size_t)s * (BERT / 4);
                a0 -= rp[l]; a1 -= rp[64 + l]; a2 -= rp[128 + l];
            }
        }
    }

    __shared__ float part[4][BERT];
    __shared__ float cw[4], tw[4];
    float* pw = part[w];
    ((v4f*)pw)[l]       = a0;
    ((v4f*)pw)[64 + l]  = a1;
    ((v4f*)pw)[128 + l] = a2;
    if (l == 0) { cw[w] = cnt; tw[w] = ts; }
    __syncthreads();

    float* Ao = A + (size_t)br * BERT;
    for (int c = tid; c < BERT; c += 256)
        Ao[c] = (part[0][c] + part[1][c]) + (part[2][c] + part[3][c]);
    if (tid == 0) {
        cnt_g[br]  = (cw[0] + cw[1]) + (cw[2] + cw[3]);
        tsum_g[br] = (tw[0] + tw[1]) + (tw[2] + tw[3]);
    }
}

// K2: grid 256 = (b, q) with q = h-quarter of 64 columns. Each block:
//   M[b,:] = sum_r (rm_r / max(cnt_r,1e-9)) * A[b,r,:]   (redundant x4, cheap)
//   p_hn[b,h] = (M.W[:,h] + b_proj[h]*qsum) / rden   for h in [q*64, q*64+64)
//   4-way k-split over d (serial depth 192) for load-latency hiding.
//   Block q==0 additionally emits uf = normalize(user_feats[b]) * user_w.
__global__ __launch_bounds__(256) void k2_gemm(
    const float* __restrict__ A, const float* __restrict__ cnt_g,
    const float* __restrict__ tsum_g, const float* __restrict__ W_proj,
    const float* __restrict__ b_proj, const float* __restrict__ user_feats,
    const float* __restrict__ user_w, float* __restrict__ pb_out) {
    int b   = blockIdx.x >> 2;
    int q   = blockIdx.x & 3;
    int tid = threadIdx.x;

    __shared__ float M[BERT];
    __shared__ float g[NR];
    __shared__ float scal[2];   // [0]=rden, [1]=qsum
    __shared__ float red[256];

    if (tid < NR) {
        float c  = cnt_g[b * NR + tid];
        float t  = tsum_g[b * NR + tid];
        float rm = (t != 0.0f) ? 1.0f : 0.0f;
        float den = fmaxf(c, 1e-9f);
        g[tid]        = rm / den;
        red[tid]      = rm;
        red[NR + tid] = rm * (c / den);
    }
    __syncthreads();
    if (tid == 0) {
        float srm = 0.f, sq = 0.f;
        for (int r = 0; r < NR; ++r) { srm += red[r]; sq += red[NR + r]; }
        scal[0] = fmaxf(srm, 1e-9f);
        scal[1] = sq;
    }
    for (int c = tid; c < BERT; c += 256) {
        float m = 0.f;
        #pragma unroll
        for (int r = 0; r < NR; ++r)
            m += g[r] * A[(size_t)(b * NR + r) * BERT + c];
        M[c] = m;
    }
    __syncthreads();   // M + scal visible

    // k-split dot: thread = (ks = tid>>6) x (hl = tid&63); d-slice of 192
    int hl = tid & 63;
    int ks = tid >> 6;
    int h  = q * 64 + hl;
    {
        const float* Wc = W_proj + h;
        float acc = 0.f;
        int d0 = ks * 192;
        #pragma unroll 16
        for (int j = 0; j < 192; ++j)
            acc += M[d0 + j] * Wc[(size_t)(d0 + j) * HID];
        red[tid] = acc;
    }
    __syncthreads();
    if (tid < 64) {
        float s = (red[tid] + red[64 + tid]) + (red[128 + tid] + red[192 + tid]);
        int hh = q * 64 + tid;
        pb_out[b * PBD + hh] = (s + b_proj[hh] * scal[1]) / scal[0];
    }

    if (q == 0) {
        __syncthreads();
        if (tid == 0) {
            float s = 0.f;
            for (int j = 0; j < NUFD; ++j) {
                float v = user_feats[b * NUFD + j];
                s += v * v;
            }
            red[0] = 1.0f / fmaxf(sqrtf(s), 1e-12f);
        }
        __syncthreads();
        if (tid < NUFD)
            pb_out[b * PBD + HID + tid] =
                user_feats[b * NUFD + tid] * red[0] * user_w[tid];
    }
}

// K3: r_stars[b] = selu(pb[b].W_rff + b_rff);
//     h_n = mean_b pb; p_stars = selu(h_n @ W_pff + b_pff)
__global__ __launch_bounds__(320) void k3_final(
    const float* __restrict__ pb, const float* __restrict__ W_rff,
    const float* __restrict__ b_rff, const float* __restrict__ W_pff,
    const float* __restrict__ b_pff, float* __restrict__ out) {
    __shared__ float hn[PBD];
    int tid = threadIdx.x;
    if (tid < PBD) {
        float s = 0.f;
        #pragma unroll 8
        for (int b = 0; b < NB; ++b) s += pb[b * PBD + tid];
        hn[tid] = s * (1.0f / NB);
    }
    __syncthreads();
    if (tid < NB) {
        int b = tid;
        float acc = 0.f;
        #pragma unroll 12
        for (int j = 0; j < PBD; ++j) acc += pb[b * PBD + j] * W_rff[j];
        out[NLAB + b] = selu_f(acc + b_rff[0]);
    } else if (tid >= 64 && tid < 64 + NLAB) {
        int lab = tid - 64;
        float acc = 0.f;
        #pragma unroll 12
        for (int j = 0; j < PBD; ++j) acc += hn[j] * W_pff[j * NLAB + lab];
        out[lab] = selu_f(acc + b_pff[lab]);
    }
}

extern "C" void kernel_launch(void* const* d_in, const int* in_sizes, int n_in,
                              void* d_out, int out_size, void* d_ws, size_t ws_size,
                              hipStream_t stream) {
    const float* inputs     = (const float*)d_in[0];
    const float* user_feats = (const float*)d_in[1];
    const float* W_proj     = (const float*)d_in[2];
    const float* b_proj     = (const float*)d_in[3];
    const float* W_rff      = (const float*)d_in[4];
    const float* b_rff      = (const float*)d_in[5];
    const float* W_pff      = (const float*)d_in[6];
    const float* b_pff      = (const float*)d_in[7];
    const float* user_w     = (const float*)d_in[8];
    float* out = (float*)d_out;     // [0..8]=p_stars, [9..72]=r_stars
    float* ws  = (float*)d_ws;

    float* A      = ws + WS_A;
    float* colsum = ws + WS_COLSUM;
    float* sumb   = ws + WS_SUMB;
    float* cntg   = ws + WS_CNT;
    float* tsumg  = ws + WS_TSUM;
    float* pb     = ws + WS_PB;

    hipLaunchKernelGGL(k0_colsum, dim3(97), dim3(256), 0, stream,
                       W_proj, b_proj, colsum, sumb);
    hipLaunchKernelGGL(k1_reduce, dim3(NB * NR), dim3(256), 0, stream,
                       inputs, colsum, sumb, A, cntg, tsumg);
    hipLaunchKernelGGL(k2_gemm, dim3(NB * 4), dim3(256), 0, stream,
                       A, cntg, tsumg, W_proj, b_proj, user_feats, user_w, pb);
    hipLaunchKernelGGL(k3_final, dim3(1), dim3(320), 0, stream,
                       pb, W_rff, b_rff, W_pff, b_pff, out);
}